// Round 3
// baseline (253.000 us; speedup 1.0000x reference)
//
#include <hip/hip_runtime.h>
#include <math.h>

// FastLearnableEMA: y[b,t,c] = cumsum_t(x * w) / max(a^t, 1e-8)
//   a = clamp(sigmoid(logit_alpha), 1e-4, 1-1e-4)      [C]
//   w[t] = a^t * (t==0 ? 1 : (1-a))
// B=32, T=2048, C=512, fp32. Memory-bound, 268 MB HBM floor (~42 us @6.3TB/s).
//
// Hierarchical scan, 2 kernels:
//  A (partials): 512 blocks x 4 waves; wave = (t-chunk of 64, channel-half);
//     lane holds 4 consecutive channels -> float4 loads (1KB/wave-instr).
//     Writes per-chunk weighted sums (global-weight space) to ws [B][32][C].
//  C (apply): same mapping; prefix = sum of <32 ws entries (L2-resident),
//     re-scan chunk (x re-read hits Infinity Cache - verified by R1 FETCH),
//     write y with nontemporal stores so y doesn't evict x from LLC.

#define B_ 32
#define T_ 2048
#define C_ 512
#define TB 64
#define NTB (T_ / TB)   // 32 chunks

typedef float f32x4 __attribute__((ext_vector_type(4)));  // native vec for NT store

__device__ __forceinline__ float clamp_sig(float z) {
    float a = 1.0f / (1.0f + expf(-z));
    return fminf(fmaxf(a, 1e-4f), 1.0f - 1e-4f);
}

__global__ __launch_bounds__(256, 2)
void ema_partials(const float* __restrict__ x,
                  const float* __restrict__ la,
                  float* __restrict__ ws) {
    const int tid = threadIdx.x;
    const int wv = tid >> 6, ln = tid & 63;
    const int b  = blockIdx.x >> 4;          // 16 chunk-pairs per b
    const int pr = blockIdx.x & 15;
    const int tb = (pr << 1) | (wv >> 1);    // 0..31
    const int c0 = ((wv & 1) << 8) | (ln << 2);
    const int t0 = tb * TB;

    const float4 z4 = *(const float4*)(la + c0);
    float a[4], oma[4], ap[4];
    const float zz[4] = {z4.x, z4.y, z4.z, z4.w};
    #pragma unroll
    for (int j = 0; j < 4; ++j) {
        a[j]   = clamp_sig(zz[j]);
        oma[j] = 1.0f - a[j];
        ap[j]  = exp2f((float)t0 * log2f(a[j]));   // a^t0 (underflow->0 ok)
    }

    const float4* __restrict__ xp =
        (const float4*)(x + ((size_t)b * T_ + t0) * C_ + c0);
    float s[4] = {0.f, 0.f, 0.f, 0.f};
    #pragma unroll 8
    for (int i = 0; i < TB; ++i) {
        const float4 xv = xp[(size_t)i * (C_ >> 2)];
        const bool z0 = (t0 + i) == 0;
        float w0 = z0 ? 1.0f : ap[0] * oma[0];
        float w1 = z0 ? 1.0f : ap[1] * oma[1];
        float w2 = z0 ? 1.0f : ap[2] * oma[2];
        float w3 = z0 ? 1.0f : ap[3] * oma[3];
        s[0] = fmaf(xv.x, w0, s[0]);
        s[1] = fmaf(xv.y, w1, s[1]);
        s[2] = fmaf(xv.z, w2, s[2]);
        s[3] = fmaf(xv.w, w3, s[3]);
        #pragma unroll
        for (int j = 0; j < 4; ++j) ap[j] *= a[j];
    }
    *(float4*)(ws + (size_t)(b * NTB + tb) * C_ + c0) =
        make_float4(s[0], s[1], s[2], s[3]);
}

__global__ __launch_bounds__(256, 2)
void ema_apply(const float* __restrict__ x,
               const float* __restrict__ la,
               const float* __restrict__ ws,
               float* __restrict__ y) {
    const int tid = threadIdx.x;
    const int wv = tid >> 6, ln = tid & 63;
    const int b  = blockIdx.x >> 4;
    const int pr = blockIdx.x & 15;
    const int tb = (pr << 1) | (wv >> 1);
    const int c0 = ((wv & 1) << 8) | (ln << 2);
    const int t0 = tb * TB;

    const float4 z4 = *(const float4*)(la + c0);
    float a[4], oma[4], ap[4], inva[4], invap[4];
    const float zz[4] = {z4.x, z4.y, z4.z, z4.w};
    #pragma unroll
    for (int j = 0; j < 4; ++j) {
        a[j]     = clamp_sig(zz[j]);
        oma[j]   = 1.0f - a[j];
        const float l2a = log2f(a[j]);
        ap[j]    = exp2f((float)t0 * l2a);
        invap[j] = exp2f(-(float)t0 * l2a);  // overflow->inf ok (clamped below)
        inva[j]  = 1.0f / a[j];
    }

    // exclusive prefix over earlier chunks (ws is 2MB -> L2-resident)
    float S[4] = {0.f, 0.f, 0.f, 0.f};
    for (int q = 0; q < tb; ++q) {
        const float4 p = *(const float4*)(ws + (size_t)(b * NTB + q) * C_ + c0);
        S[0] += p.x; S[1] += p.y; S[2] += p.z; S[3] += p.w;
    }

    const float4* __restrict__ xp =
        (const float4*)(x + ((size_t)b * T_ + t0) * C_ + c0);
    float* __restrict__ yp = y + ((size_t)b * T_ + t0) * C_ + c0;

    #pragma unroll 4
    for (int i = 0; i < TB; ++i) {
        const float4 xv = xp[(size_t)i * (C_ >> 2)];
        const bool z0 = (t0 + i) == 0;
        float w0 = z0 ? 1.0f : ap[0] * oma[0];
        float w1 = z0 ? 1.0f : ap[1] * oma[1];
        float w2 = z0 ? 1.0f : ap[2] * oma[2];
        float w3 = z0 ? 1.0f : ap[3] * oma[3];
        S[0] = fmaf(xv.x, w0, S[0]);
        S[1] = fmaf(xv.y, w1, S[1]);
        S[2] = fmaf(xv.z, w2, S[2]);
        S[3] = fmaf(xv.w, w3, S[3]);
        // 1/max(a^t,1e-8) == min(a^-t, 1e8); inf clamps to 1e8 (matches EPS)
        f32x4 out;
        out.x = S[0] * fminf(invap[0], 1e8f);
        out.y = S[1] * fminf(invap[1], 1e8f);
        out.z = S[2] * fminf(invap[2], 1e8f);
        out.w = S[3] * fminf(invap[3], 1e8f);
        __builtin_nontemporal_store(out, (f32x4*)(yp + (size_t)i * C_));
        #pragma unroll
        for (int j = 0; j < 4; ++j) { ap[j] *= a[j]; invap[j] *= inva[j]; }
    }
}

extern "C" void kernel_launch(void* const* d_in, const int* in_sizes, int n_in,
                              void* d_out, int out_size, void* d_ws, size_t ws_size,
                              hipStream_t stream) {
    const float* x  = (const float*)d_in[0];   // [32, 2048, 512] fp32
    const float* la = (const float*)d_in[1];   // [512] fp32
    float* y  = (float*)d_out;                 // [32, 2048, 512] fp32
    float* ws = (float*)d_ws;                  // needs B*NTB*C*4 = 2 MB

    dim3 grid(B_ * (NTB / 2));   // 512 blocks
    dim3 block(256);             // 4 waves
    hipLaunchKernelGGL(ema_partials, grid, block, 0, stream, x, la, ws);
    hipLaunchKernelGGL(ema_apply,    grid, block, 0, stream, x, la, ws, y);
}